// Round 15
// baseline (298.325 us; speedup 1.0000x reference)
//
#include <hip/hip_runtime.h>

#define Bq   8
#define Tq   16
#define Nq   1024
#define Cq   48
#define Gq   32
#define Hq   150
#define H3q  450
#define TAq  32
#define OUTq 1024
#define BTq  128
#define NBLK (4 * BTq)   // 512 blocks; 2 blocks/CU via LDS<80KB IF VGPR<=128 (runtime decision)
#define THREADS 512

#define NC_CAP 128
#define NM_CAP 64
#define NACT   (2 * NC_CAP)
#define MTILE  16
#define NMH4   (NM_CAP / 4)   // per-quarter m-row capacity
#define CHUNK  16             // GRU1B chain-row batch

__device__ __forceinline__ float lrelu(float x){ return x > 0.f ? x : 0.01f * x; }
__device__ __forceinline__ float sigm(float x){ return 1.f / (1.f + expf(-x)); }

// -------- cross-block data: agent-scope relaxed atomics (sc1 -> LLC); no fences anywhere ----
__device__ __align__(16) int   g_n1[BTq], g_n23[BTq], g_nchain[BTq], g_nchain2[BTq];
__device__ __align__(16) int   g_list1[BTq][NM_CAP];
__device__ __align__(16) int   g_list23[BTq][NM_CAP];   // row | (m2 ? 0x400 : 0)
__device__ __align__(16) int   g_mapc[BTq][Nq];
__device__ __align__(16) int   g_mapn[BTq][Nq];
__device__ __align__(16) int   g_chain[BTq][NM_CAP];    // (i_slot << 16) | prev_slot
__device__ __align__(16) int   g_chain2[BTq][NM_CAP];
__device__ __align__(16) int   g_cls[BTq][NM_CAP];
__device__ __align__(16) float g_co[BTq][NC_CAP][Gq];
__device__ __align__(16) float g_no[BTq][NC_CAP][Gq];
__device__ __align__(16) float g_hm23[BTq][NM_CAP][Hq];
__device__ __align__(16) float g_om23p4[4][BTq][Hq];    // per-quarter partial max
__device__ __align__(16) float g_hm1[BTq][NM_CAP][Hq];
__device__ __align__(16) float g_om1p4[4][BTq][Hq];     // per-quarter partial max
__device__ __align__(16) float g_om1c[BTq][Hq];

template<typename T>
__device__ __forceinline__ T gld(const T* p){
    return __hip_atomic_load(p, __ATOMIC_RELAXED, __HIP_MEMORY_SCOPE_AGENT);
}
template<typename T>
__device__ __forceinline__ void gst(T* p, T v){
    __hip_atomic_store(p, v, __ATOMIC_RELAXED, __HIP_MEMORY_SCOPE_AGENT);
}

// -------- per-block dataflow flags ------------------------------------------------------------
// Progress per launch: +1 CO, +2 MID, +3 GRU1; quarter-0 blocks +4 after GRU1B; chain blocks
// (blk%64==0) +5 after FIN-A; ALL blocks run FIN-B and end at +6 (replay-safe).
// No-deadlock note at 1 block/CU fallback: waits target only same-group-of-4 siblings
// (groups never straddle the 256-resident boundary) and lower-bt blocks.
__device__ unsigned int g_done[NBLK][16];

__device__ __forceinline__ void publish(unsigned int val){
    asm volatile("s_waitcnt vmcnt(0)" ::: "memory");   // sc1 stores committed at L3
    __syncthreads();
    if (threadIdx.x == 0)
        __hip_atomic_store(&g_done[blockIdx.x][0], val,
                           __ATOMIC_RELAXED, __HIP_MEMORY_SCOPE_AGENT);
}

__device__ __forceinline__ void spin_ge(int b2, unsigned int tgt){
    while ((int)(__hip_atomic_load(&g_done[b2][0],
                                   __ATOMIC_RELAXED, __HIP_MEMORY_SCOPE_AGENT) - tgt) < 0)
        __builtin_amdgcn_s_sleep(4);
}

// inline gi helper: gi = bi + co @ Wi at column h
__device__ __forceinline__ void gi3(const float* co_row, const float* Wi, const float* bi, int h,
                                    float& gr, float& gz, float& gn){
    gr = bi[h]; gz = bi[Hq + h]; gn = bi[2 * Hq + h];
    #pragma unroll
    for (int g = 0; g < Gq; ++g){
        float c = co_row[g];
        const float* w = Wi + g * H3q + h;
        gr += c * w[0];
        gz += c * w[Hq];
        gn += c * w[2 * Hq];
    }
}

// -------- L3 warm-stream --------------------------------------------------------------------
#define WARM(ptr, nfloats) { int nv_ = (nfloats) >> 2; \
    for (int i4_ = blk * THREADS + tid; i4_ < nv_; i4_ += NBLK * THREADS){ \
        float4 v_ = ((const float4*)(ptr))[i4_]; \
        wacc += v_.x + v_.y + v_.z + v_.w; } }

// -------- phase-overlaid LDS (max member ~72.9 KB -> 2 blocks/CU if VGPR <= 128) ------------
union SharedU {
    struct {                                   // CO (~58 KB)
        unsigned char cf[Nq], nf[Nq];
        short lc[NC_CAP], ln[NC_CAP];
        short act[NACT];
        float Wg[Cq][Gq];
        float Pact[NACT][Gq];
        float A[MTILE][NACT];
    } co;
    struct {                                   // MID (~72.9 KB)
        unsigned char f1[Nq], f2[Nq], f3[Nq];
        short l1[NM_CAP], l23[NM_CAP];
        unsigned char wm[NMH4];
        union {                                // co23/qr dead >=2 barriers before hm written
            struct { float co23[NM_CAP][Gq]; float qr[NM_CAP][Gq]; } in;
            float hm[NMH4][Hq];
        } u;
        float q[NMH4][TAq + 1];
        float k[NM_CAP][TAq + 1];
        float s[NMH4][NM_CAP + 1];
        float vv[NM_CAP][Hq];
    } mid;
    struct {                                   // GRU1 (~37.8 KB)
        short map1p[Nq], map23p[Nq];
        short l1[NM_CAP];
        unsigned char cls[NM_CAP];
        int   m23l[NM_CAP];
        float co1[NMH4][Gq];
        float hb[Hq];
        float ghf[H3q];
        float gi[NMH4][H3q];
    } g1;
    struct {                                   // GRU1B batched (~51 KB)
        int   proc[NM_CAP];
        float hb[CHUNK][Hq];
        float co[CHUNK][Gq];
        float ghf[CHUNK][H3q];
        float hm[CHUNK][Hq];
        float cmax[Hq];
    } g1b;
    struct {                                   // FIN (~15.6 KB)
        int   nch2[Tq];
        float co[Gq];
        float hb[Hq];
        float ghf[H3q];
        float outs[Tq][Hq];
        float wdc[Hq];
        float score[Tq];
        float pooled[Hq];
        float cpart[16][33];                   // classifier partials (16 outputs x 32 segs)
    } fin;
};

// -------- CO tile helpers: quarter rows (r == qtr mod 4), double-buffered adj gather ---------
// lim <= MTILE*NACT = 4096 = 8*512 -> 8 regs per thread exactly
#define CO_PREFETCH(P, kk) { int rbase_ = qtr + (kk) * 4 * MTILE; \
    int ntile_ = min(MTILE, (total - rbase_ + 3) / 4); int lim_ = ntile_ * total; \
    _Pragma("unroll") for (int u = 0; u < 8; ++u){ int idx_ = tid + u * THREADS; \
        if (idx_ < lim_){ int ti_ = idx_ / total, j_ = idx_ - ti_ * total; \
            P[u] = adj[(size_t)sh.co.act[rbase_ + 4 * ti_] * Nq + sh.co.act[j_]]; } } }

#define CO_STORE(P, kk) { int rbase_ = qtr + (kk) * 4 * MTILE; \
    int ntile_ = min(MTILE, (total - rbase_ + 3) / 4); int lim_ = ntile_ * total; \
    _Pragma("unroll") for (int u = 0; u < 8; ++u){ int idx_ = tid + u * THREADS; \
        if (idx_ < lim_){ int ti_ = idx_ / total, j_ = idx_ - ti_ * total; \
            sh.co.A[ti_][j_] = P[u]; } } }

#define CO_COMPUTE(kk) { int rbase_ = qtr + (kk) * 4 * MTILE; \
    int ntile_ = min(MTILE, (total - rbase_ + 3) / 4); \
    if (grp < ntile_){ int r_ = rbase_ + 4 * grp; float agg_ = 0.f; \
        _Pragma("unroll 4") for (int j_ = 0; j_ < total; ++j_) \
            agg_ += sh.co.A[grp][j_] * sh.co.Pact[j_][g]; \
        float v_ = lrelu(sh.co.Pact[r_][g] + agg_ + bgv); \
        if (r_ < nc) gst(&g_co[bt][r_][g], v_); else gst(&g_no[bt][r_ - nc][g], v_); } }

__global__ __launch_bounds__(THREADS, 1) void k_fused(   // NO min-wave forcing: keep 128 VGPR
    const float* code_x, const float* divided, const float* neighbors,
    const int* lens, const float* adj, const float* c_emb, const float* n_emb,
    const float* u_emb, const float* Wg, const float* bg,
    const float* Wi, const float* bi, const float* Wh, const float* bh,
    const float* Wq_, const float* bq_, const float* Wk_, const float* bk_,
    const float* Wv_, const float* bv_, const float* Wd, const float* bd,
    const float* ctx, const float* Wc, const float* bc, float* out)
{
    __shared__ SharedU sh;
    __shared__ int s_n0, s_n1v, s_i2;
    const int tid = threadIdx.x;
    const int blk = blockIdx.x;
    const int bt   = blk >> 2;
    const int qtr  = blk & 3;
    const int sb   = blk & ~3;        // sibling base (4 blocks of this bt)
    const int t    = bt % Tq;
    const int btp  = bt - 1;
    const unsigned int bar0 = __hip_atomic_load(&g_done[blk][0],
                                                __ATOMIC_RELAXED, __HIP_MEMORY_SCOPE_AGENT);

    // ---- L3 warm-stream (~8.3 MB across 262144 threads) ----
    float wacc = 0.f;
    WARM(code_x,    BTq * Nq);
    WARM(neighbors, BTq * Nq);
    WARM(adj,       Nq * Nq);
    WARM(divided,   BTq * Nq * 3);
    WARM(c_emb,     Nq * Cq);
    WARM(n_emb,     Nq * Cq);
    WARM(u_emb,     Nq * Gq);
    WARM(Wi,        Gq * H3q);
    WARM(Wh,        Hq * H3q);
    WARM(Wc,        Hq * OUTq);
    WARM(Wv_,       Gq * Hq);
    WARM(Wd,        Hq * TAq);

    // ================= Phase CO (all 512 blocks; 4 per (b,t), rows r==qtr mod 4) ==============
    {
        int wave = tid >> 6, lane = tid & 63;
        for (int n = tid; n < Nq; n += THREADS){
            sh.co.cf[n] = (code_x[bt * Nq + n]    > 0.f) ? 1 : 0;
            sh.co.nf[n] = (neighbors[bt * Nq + n] > 0.f) ? 1 : 0;
        }
        for (int i = tid; i < Cq * Gq; i += THREADS) (&sh.co.Wg[0][0])[i] = Wg[i];
        __syncthreads();
        if (wave == 0){           // compact c-active rows (ballot over LDS flags)
            int base = 0;
            for (int start = 0; start < Nq; start += 64){
                int n = start + lane;
                int pred = sh.co.cf[n];
                unsigned long long mm = __ballot(pred != 0);
                int pos = base + (int)__popcll(mm & ((1ull << lane) - 1ull));
                if (pred && pos < NC_CAP) sh.co.lc[pos] = (short)n;
                base += (int)__popcll(mm);
            }
            if (lane == 0) s_n0 = min(base, NC_CAP);
        } else if (wave == 1){    // compact nb-active rows
            int base = 0;
            for (int start = 0; start < Nq; start += 64){
                int n = start + lane;
                int pred = sh.co.nf[n];
                unsigned long long mm = __ballot(pred != 0);
                int pos = base + (int)__popcll(mm & ((1ull << lane) - 1ull));
                if (pred && pos < NC_CAP) sh.co.ln[pos] = (short)n;
                base += (int)__popcll(mm);
            }
            if (lane == 0) s_n1v = min(base, NC_CAP);
        } else {                  // clear map (qtr 0 -> mapc, qtr 1 -> mapn; 384 threads)
            if (qtr == 0)      for (int n = tid - 128; n < Nq; n += 384) gst(&g_mapc[bt][n], -1);
            else if (qtr == 1) for (int n = tid - 128; n < Nq; n += 384) gst(&g_mapn[bt][n], -1);
        }
        __syncthreads();
        int nc = s_n0, nn = s_n1v, total = nc + nn;

        for (int i = tid; i < total; i += THREADS) sh.co.act[i] = (i < nc) ? sh.co.lc[i] : sh.co.ln[i - nc];
        if (qtr == 0)      for (int i = tid; i < nc; i += THREADS) gst(&g_mapc[bt][sh.co.lc[i]], i);
        else if (qtr == 1) for (int i = tid; i < nn; i += THREADS) gst(&g_mapn[bt][sh.co.ln[i]], i);
        __syncthreads();

        // Pact[i][g] = emb[act[i]] @ Wg
        for (int idx = tid; idx < total * Gq; idx += THREADS){
            int i = idx >> 5, g = idx & 31;
            int row = sh.co.act[i];
            const float* e = (i < nc) ? (c_emb + row * Cq) : (n_emb + row * Cq);
            float acc = 0.f;
            #pragma unroll
            for (int c = 0; c < Cq; ++c) acc += e[c] * sh.co.Wg[c][g];
            sh.co.Pact[i][g] = acc;
        }
        __syncthreads();

        // double-buffered gathered-GEMM over my quarter's rows
        int g = tid & 31, grp = tid >> 5;
        float bgv = bg[g];
        int ntiles = (total > qtr) ? (total - qtr + 4 * MTILE - 1) / (4 * MTILE) : 0;
        float pA[8], pB[8];
        if (ntiles > 0) CO_PREFETCH(pA, 0);
        for (int k = 0; k < ntiles; ){
            CO_STORE(pA, k);
            __syncthreads();
            if (k + 1 < ntiles) CO_PREFETCH(pB, k + 1);
            CO_COMPUTE(k);
            __syncthreads();
            ++k; if (k >= ntiles) break;
            CO_STORE(pB, k);
            __syncthreads();
            if (k + 1 < ntiles) CO_PREFETCH(pA, k + 1);
            CO_COMPUTE(k);
            __syncthreads();
            ++k;
        }
    }
    asm volatile("" :: "v"(wacc));   // keep warm loads live (rule #17)
    publish(bar0 + 1);
    // T14: divided prefetch flies during the spins below
    float dv[6];
    #pragma unroll
    for (int u = 0; u < 6; ++u) dv[u] = divided[(size_t)bt * (Nq * 3) + tid + u * THREADS];
    if (tid < 4 && tid != qtr) spin_ge(sb + tid, bar0 + 1);              // 3 siblings
    if (t > 0 && tid >= 4 && tid < 8) spin_ge(4 * btp + (tid - 4), bar0 + 1);  // 4 of btp
    __syncthreads();

    // ================= Phase MID (all 512 blocks; query rows i==qtr mod 4) ====================
    {
        int wave = tid >> 6, lane = tid & 63;
        #pragma unroll
        for (int u = 0; u < 6; ++u){
            int idx = tid + u * THREADS;
            int n = idx / 3, c = idx - n * 3;
            unsigned char f = (dv[u] > 0.f) ? 1 : 0;
            if (c == 0) sh.mid.f1[n] = f;
            else if (c == 1) sh.mid.f2[n] = f;
            else sh.mid.f3[n] = f;
        }
        __syncthreads();
        if (wave == 0){           // m1 list
            int base = 0;
            for (int start = 0; start < Nq; start += 64){
                int n = start + lane;
                int pred = sh.mid.f1[n];
                unsigned long long mm = __ballot(pred != 0);
                int pos = base + (int)__popcll(mm & ((1ull << lane) - 1ull));
                if (pred && pos < NM_CAP) sh.mid.l1[pos] = (short)n;
                base += (int)__popcll(mm);
            }
            if (lane == 0) s_n0 = min(base, NM_CAP);
        } else if (wave == 1){    // m23 list with m2 tag
            int base = 0;
            for (int start = 0; start < Nq; start += 64){
                int n = start + lane;
                int m2 = sh.mid.f2[n], m3 = sh.mid.f3[n];
                int pred = m2 | m3;
                unsigned long long mm = __ballot(pred != 0);
                int pos = base + (int)__popcll(mm & ((1ull << lane) - 1ull));
                if (pred && pos < NM_CAP) sh.mid.l23[pos] = (short)(n | (m2 ? 0x400 : 0));
                base += (int)__popcll(mm);
            }
            if (lane == 0) s_n1v = min(base, NM_CAP);
        }
        __syncthreads();
        int n1 = s_n0, n23 = s_n1v;
        if (qtr == 0){
            for (int i = tid; i < n1;  i += THREADS) gst(&g_list1[bt][i],  (int)sh.mid.l1[i]);
            for (int i = tid; i < n23; i += THREADS) gst(&g_list23[bt][i], (int)sh.mid.l23[i]);
            if (tid == 0){ gst(&g_n1[bt], n1); gst(&g_n23[bt], n23); }
        }
        if (t != 0 && n23 != 0){
            int nMy = (n23 > qtr) ? ((n23 - qtr + 3) >> 2) : 0;   // rows i with (i&3)==qtr

            for (int il = tid; il < nMy; il += THREADS){
                int row = sh.mid.l23[4 * il + qtr] & 1023;
                unsigned char wmv = 0;
                if (t < Tq - 1) wmv = (divided[((size_t)(bt + 1) * Nq + row) * 3] > 0.f) ? 1 : 0;
                sh.mid.wm[il] = wmv;
            }
            for (int idx = tid; idx < n23 * Gq; idx += THREADS){
                int i = idx >> 5, g = idx & 31;
                sh.mid.u.in.co23[i][g] = gld(&g_co[bt][gld(&g_mapc[bt][sh.mid.l23[i] & 1023])][g]);
            }
            for (int idx = tid; idx < n23 * Gq; idx += THREADS){
                int i = idx >> 5, g = idx & 31;
                int e = sh.mid.l23[i], row = e & 1023;
                float qv;
                if (e & 0x400){
                    int slot = gld(&g_mapn[btp][row]);
                    qv = (slot >= 0) ? gld(&g_no[btp][slot][g]) : lrelu(bg[g]);
                } else {
                    qv = u_emb[row * Gq + g];
                }
                sh.mid.u.in.qr[i][g] = qv;
            }
            __syncthreads();
            for (int idx = tid; idx < n23 * TAq; idx += THREADS){
                int i = idx >> 5, a = idx & 31;
                float acck = bk_[a];
                #pragma unroll
                for (int g = 0; g < Gq; ++g) acck += sh.mid.u.in.co23[i][g] * Wk_[g * TAq + a];
                sh.mid.k[i][a] = acck;
            }
            for (int idx = tid; idx < nMy * TAq; idx += THREADS){
                int il = idx >> 5, a = idx & 31;
                int i = 4 * il + qtr;
                float accq = bq_[a];
                #pragma unroll
                for (int g = 0; g < Gq; ++g) accq += sh.mid.u.in.qr[i][g] * Wq_[g * TAq + a];
                sh.mid.q[il][a] = accq;
            }
            for (int idx = tid; idx < n23 * Hq; idx += THREADS){
                int i = idx / Hq, h = idx % Hq;
                float acc = bv_[h];
                #pragma unroll
                for (int g = 0; g < Gq; ++g) acc += sh.mid.u.in.qr[i][g] * Wv_[g * Hq + h];
                sh.mid.vv[i][h] = acc;
            }
            __syncthreads();   // last co23/qr read above; hm overlay written below

            const float scale = 0.17677669529663687f;   // 1/sqrt(32)
            for (int idx = tid; idx < nMy * n23; idx += THREADS){
                int il = idx / n23, j = idx % n23;
                float acc = 0.f;
                #pragma unroll
                for (int a = 0; a < TAq; ++a) acc += sh.mid.q[il][a] * sh.mid.k[j][a];
                sh.mid.s[il][j] = acc * scale;
            }
            __syncthreads();
            for (int il = tid; il < nMy; il += THREADS){
                float mx = -1e30f;
                for (int j = 0; j < n23; ++j) mx = fmaxf(mx, sh.mid.s[il][j]);
                float sum = 0.f;
                for (int j = 0; j < n23; ++j){ float e = expf(sh.mid.s[il][j] - mx); sh.mid.s[il][j] = e; sum += e; }
                float inv = 1.f / sum;
                for (int j = 0; j < n23; ++j) sh.mid.s[il][j] *= inv;
            }
            __syncthreads();
            for (int idx = tid; idx < nMy * Hq; idx += THREADS){
                int il = idx / Hq, h = idx % Hq;
                float acc = 0.f;
                for (int j = 0; j < n23; ++j) acc += sh.mid.s[il][j] * sh.mid.vv[j][h];
                sh.mid.u.hm[il][h] = tanhf(acc);
            }
            __syncthreads();
            for (int idx = tid; idx < nMy * Hq; idx += THREADS){
                int il = idx / Hq, h = idx % Hq;
                if (sh.mid.wm[il]) gst(&g_hm23[bt][4 * il + qtr][h], sh.mid.u.hm[il][h]);
            }
            for (int h = tid; h < Hq; h += THREADS){
                float mx = -1e30f;
                for (int il = 0; il < nMy; ++il) mx = fmaxf(mx, sh.mid.u.hm[il][h]);
                gst(&g_om23p4[qtr][bt][h], mx);
            }
        }
    }
    publish(bar0 + 2);
    if (tid < 4 && tid != qtr) spin_ge(sb + tid, bar0 + 2);
    if (t > 0 && tid >= 4 && tid < 8) spin_ge(4 * btp + (tid - 4), bar0 + 2);
    __syncthreads();

    // ================= Phase GRU1 (all 512 blocks; m1 rows i==qtr mod 4) ======================
    {
        int n1 = gld(&g_n1[bt]);
        int nMy = (n1 > qtr) ? ((n1 - qtr + 3) >> 2) : 0;
        for (int n = tid; n < Nq; n += THREADS){
            if (t >= 1) sh.g1.map1p[n] = -1;
            if (t >= 2) sh.g1.map23p[n] = -1;
        }
        for (int i = tid; i < n1; i += THREADS) sh.g1.l1[i] = (short)gld(&g_list1[bt][i]);
        __syncthreads();
        if (t >= 1){
            int n1p = gld(&g_n1[btp]);
            for (int i = tid; i < n1p; i += THREADS) sh.g1.map1p[gld(&g_list1[btp][i])] = (short)i;
            if (t >= 2){
                int n23p = gld(&g_n23[btp]);
                for (int i = tid; i < n23p; i += THREADS) sh.g1.map23p[gld(&g_list23[btp][i]) & 1023] = (short)i;
            }
        }
        __syncthreads();
        if (tid < 64){                                // classify + ballot-compact
            int i = tid;
            int cls = 0, sp = -1;
            if (i < n1 && t >= 1){
                int row = sh.g1.l1[i];
                if (sh.g1.map1p[row] >= 0){ cls = 1; sp = sh.g1.map1p[row]; }
                else if (t >= 2 && sh.g1.map23p[row] >= 0){ cls = 2; sp = sh.g1.map23p[row]; }
            }
            if (i < n1) sh.g1.cls[i] = (unsigned char)cls;
            if (qtr == 0 && i < n1) gst(&g_cls[bt][i], cls);
            unsigned long long mch = __ballot(cls == 1);
            unsigned long long m23 = __ballot(cls == 2 && (i & 3) == qtr);
            int pch = (int)__popcll(mch & ((1ull << i) - 1ull));
            int p23 = (int)__popcll(m23 & ((1ull << i) - 1ull));
            if (qtr == 0 && cls == 1) gst(&g_chain[bt][pch], (i << 16) | sp);
            if (cls == 2 && (i & 3) == qtr) sh.g1.m23l[p23] = (i << 16) | sp;
            if (i == 0){
                s_i2 = (int)__popcll(m23);
                if (qtr == 0) gst(&g_nchain[bt], (int)__popcll(mch));
            }
        }
        for (int idx = tid; idx < nMy * Gq; idx += THREADS){
            int il = idx >> 5, g = idx & 31;
            sh.g1.co1[il][g] = gld(&g_co[bt][gld(&g_mapc[bt][sh.g1.l1[4 * il + qtr]])][g]);
        }
        __syncthreads();

        // cooperative gi: thread j < 450 holds Wi column in regs
        if (tid < H3q){
            float wcol[Gq];
            #pragma unroll
            for (int g = 0; g < Gq; ++g) wcol[g] = Wi[g * H3q + tid];
            float bij = bi[tid];
            for (int il = 0; il < nMy; ++il){
                float acc = bij;
                #pragma unroll
                for (int g = 0; g < Gq; ++g) acc += sh.g1.co1[il][g] * wcol[g];
                sh.g1.gi[il][tid] = acc;
            }
        }
        __syncthreads();

        // plain rows: hp = 0, gh = bias only
        for (int idx = tid; idx < nMy * Hq; idx += THREADS){
            int il = idx / Hq, h = idx % Hq;
            int i = 4 * il + qtr;
            if (sh.g1.cls[i] != 0) continue;
            float gr = sh.g1.gi[il][h], gz = sh.g1.gi[il][Hq + h], gn = sh.g1.gi[il][2 * Hq + h];
            float r  = sigm(gr + bh[h]);
            float z  = sigm(gz + bh[Hq + h]);
            float ng = tanhf(gn + r * bh[2 * Hq + h]);
            sh.g1.gi[il][h] = (1.f - z) * ng;
        }
        __syncthreads();

        // m23-sourced rows in my quarter (~0.25 per block)
        int nf23 = s_i2;
        for (int f = 0; f < nf23; ++f){
            int pk = sh.g1.m23l[f]; int i = pk >> 16, sp = pk & 0xffff;
            int il = i >> 2;
            for (int h = tid; h < Hq; h += THREADS) sh.g1.hb[h] = gld(&g_hm23[btp][sp][h]);
            __syncthreads();
            for (int j = tid; j < H3q; j += THREADS){
                float acc = bh[j];
                for (int k2 = 0; k2 < Hq; ++k2) acc += sh.g1.hb[k2] * Wh[k2 * H3q + j];
                sh.g1.ghf[j] = acc;
            }
            __syncthreads();
            for (int h = tid; h < Hq; h += THREADS){
                float gr = sh.g1.gi[il][h], gz = sh.g1.gi[il][Hq + h], gn = sh.g1.gi[il][2 * Hq + h];
                float r  = sigm(gr + sh.g1.ghf[h]);
                float z  = sigm(gz + sh.g1.ghf[Hq + h]);
                float ng = tanhf(gn + r * sh.g1.ghf[2 * Hq + h]);
                sh.g1.gi[il][h] = (1.f - z) * ng + z * sh.g1.hb[h];
            }
            __syncthreads();
        }

        for (int idx = tid; idx < nMy * Hq; idx += THREADS){
            int il = idx / Hq, h = idx % Hq;
            int i = 4 * il + qtr;
            if (sh.g1.cls[i] != 1) gst(&g_hm1[bt][i][h], sh.g1.gi[il][h]);
        }
        for (int h = tid; h < Hq; h += THREADS){
            float mx = -1e30f;
            for (int il = 0; il < nMy; ++il)
                if (sh.g1.cls[4 * il + qtr] != 1) mx = fmaxf(mx, sh.g1.gi[il][h]);
            gst(&g_om1p4[qtr][bt][h], mx);
        }
    }
    publish(bar0 + 3);

    // ================= Phase GRU1B (quarter-0 blocks) + FIN-A (chain blocks) ===================
    if (qtr == 0){
        if (t > 0){
            if (tid < 4) spin_ge(4 * btp + tid, bar0 + 3);   // GRU1 of btp, all quarters
        }
        __syncthreads();
        {   // BATCHED chain rows (mutually independent; CHUNK at a time)
            int nch = (t > 0) ? gld(&g_nchain[bt]) : 0;
            for (int h = tid; h < Hq; h += THREADS) sh.g1b.cmax[h] = -1e30f;
            if (tid < 64){
                int c = tid;
                int pk = 0, defer = 0;
                if (c < nch){
                    pk = gld(&g_chain[bt][c]);
                    int sp = pk & 0xffff;
                    defer = (gld(&g_cls[btp][sp]) == 1) ? 1 : 0;
                }
                unsigned long long md = __ballot((c < nch) && defer);
                unsigned long long mp = __ballot((c < nch) && !defer);
                int pos  = (int)__popcll(md & ((1ull << c) - 1ull));
                int ppos = (int)__popcll(mp & ((1ull << c) - 1ull));
                if ((c < nch) && defer)  gst(&g_chain2[bt][pos], pk);
                if ((c < nch) && !defer) sh.g1b.proc[ppos] = pk;
                if (c == 0){
                    gst(&g_nchain2[bt], (int)__popcll(md));
                    s_i2 = (int)__popcll(mp);
                }
            }
            __syncthreads();
            int nproc = s_i2;
            for (int cb = 0; cb < nproc; cb += CHUNK){
                int nc2 = min(CHUNK, nproc - cb);
                for (int idx = tid; idx < nc2 * Hq; idx += THREADS){
                    int c = idx / Hq, h = idx % Hq;
                    int sp = sh.g1b.proc[cb + c] & 0xffff;
                    sh.g1b.hb[c][h] = gld(&g_hm1[btp][sp][h]);
                }
                for (int idx = tid; idx < nc2 * Gq; idx += THREADS){
                    int c = idx >> 5, g = idx & 31;
                    int i = sh.g1b.proc[cb + c] >> 16;
                    sh.g1b.co[c][g] = gld(&g_co[bt][gld(&g_mapc[bt][gld(&g_list1[bt][i])])][g]);
                }
                __syncthreads();
                for (int idx = tid; idx < nc2 * H3q; idx += THREADS){
                    int c = idx / H3q, j = idx - c * H3q;
                    float acc = bh[j];
                    for (int k2 = 0; k2 < Hq; ++k2) acc += sh.g1b.hb[c][k2] * Wh[k2 * H3q + j];
                    sh.g1b.ghf[c][j] = acc;
                }
                __syncthreads();
                for (int idx = tid; idx < nc2 * Hq; idx += THREADS){
                    int c = idx / Hq, h = idx % Hq;
                    int i = sh.g1b.proc[cb + c] >> 16;
                    float gr, gz, gn;
                    gi3(sh.g1b.co[c], Wi, bi, h, gr, gz, gn);
                    float r  = sigm(gr + sh.g1b.ghf[c][h]);
                    float z  = sigm(gz + sh.g1b.ghf[c][Hq + h]);
                    float ng = tanhf(gn + r * sh.g1b.ghf[c][2 * Hq + h]);
                    float v  = (1.f - z) * ng + z * sh.g1b.hb[c][h];
                    gst(&g_hm1[bt][i][h], v);
                    sh.g1b.hm[c][h] = v;
                }
                __syncthreads();
                for (int h = tid; h < Hq; h += THREADS){
                    float mx = sh.g1b.cmax[h];
                    for (int c = 0; c < nc2; ++c) mx = fmaxf(mx, sh.g1b.hm[c][h]);
                    sh.g1b.cmax[h] = mx;
                }
                __syncthreads();
            }
            for (int h = tid; h < Hq; h += THREADS) gst(&g_om1c[bt][h], sh.g1b.cmax[h]);
        }
        publish(bar0 + 4);

        if ((blk & 63) == 0){
            // ---- FIN-A (chain blocks): deep chains, serial over t ----
            int b = blk >> 6;
            if (tid < 16) spin_ge(64 * b + 4 * tid, bar0 + 4);   // all q0 blocks of b
            __syncthreads();
            if (tid < Tq) sh.fin.nch2[tid] = (tid > 0) ? gld(&g_nchain2[b * Tq + tid]) : 0;
            __syncthreads();
            for (int tt = 1; tt < Tq; ++tt){
                int bt2 = b * Tq + tt, btp2 = bt2 - 1;
                int nch2 = sh.fin.nch2[tt];
                for (int c = 0; c < nch2; ++c){
                    int pk = gld(&g_chain2[bt2][c]); int i = pk >> 16, sp = pk & 0xffff;
                    if (tid < Gq) sh.fin.co[tid] = gld(&g_co[bt2][gld(&g_mapc[bt2][gld(&g_list1[bt2][i])])][tid]);
                    for (int h = tid; h < Hq; h += THREADS) sh.fin.hb[h] = gld(&g_hm1[btp2][sp][h]);
                    __syncthreads();
                    for (int j = tid; j < H3q; j += THREADS){
                        float acc = bh[j];
                        for (int k2 = 0; k2 < Hq; ++k2) acc += sh.fin.hb[k2] * Wh[k2 * H3q + j];
                        sh.fin.ghf[j] = acc;
                    }
                    __syncthreads();
                    for (int h = tid; h < Hq; h += THREADS){
                        float gr, gz, gn;
                        gi3(sh.fin.co, Wi, bi, h, gr, gz, gn);
                        float r  = sigm(gr + sh.fin.ghf[h]);
                        float z  = sigm(gz + sh.fin.ghf[Hq + h]);
                        float ng = tanhf(gn + r * sh.fin.ghf[2 * Hq + h]);
                        gst(&g_hm1[bt2][i][h], (1.f - z) * ng + z * sh.fin.hb[h]);
                    }
                    __syncthreads();
                }
            }
            publish(bar0 + 5);
        }
    }

    // ================= Phase FIN-B (ALL 512 blocks; 64 per b, disjoint 16-output slices) =======
    {
        int b = blk >> 6;
        // wait: chain block of b >= +5 (implies all q0 of b >= +4); non-q0 blocks of b >= +3
        if (tid == 0) spin_ge(64 * b, bar0 + 5);
        else if (tid >= 1 && tid < 49){
            int idx = tid - 1;                   // 16 t's x 3 quarters
            int tt = idx / 3, qq = 1 + idx % 3;
            spin_ge(64 * b + 4 * tt + qq, bar0 + 3);
        }
        __syncthreads();

        if (tid < Tq) sh.fin.nch2[tid] = (tid > 0) ? gld(&g_nchain2[b * Tq + tid]) : 0;
        __syncthreads();
        // redundant (per-block) outs finalize + temporal attention; LDS-only
        for (int idx = tid; idx < Tq * Hq; idx += THREADS){
            int tt = idx / Hq, h = idx % Hq;
            int bt2 = b * Tq + tt;
            int n1 = gld(&g_n1[bt2]), n23 = (tt > 0) ? gld(&g_n23[bt2]) : 0;
            float o = 0.f;
            if (n1 > 0){
                float mx = fmaxf(fmaxf(gld(&g_om1p4[0][bt2][h]), gld(&g_om1p4[1][bt2][h])),
                                 fmaxf(gld(&g_om1p4[2][bt2][h]), gld(&g_om1p4[3][bt2][h])));
                mx = fmaxf(mx, gld(&g_om1c[bt2][h]));
                int nd = sh.fin.nch2[tt];
                for (int c = 0; c < nd; ++c){
                    int i = gld(&g_chain2[bt2][c]) >> 16;
                    mx = fmaxf(mx, gld(&g_hm1[bt2][i][h]));
                }
                o = mx;
            }
            if (n23 > 0){
                float m23x = fmaxf(fmaxf(gld(&g_om23p4[0][bt2][h]), gld(&g_om23p4[1][bt2][h])),
                                   fmaxf(gld(&g_om23p4[2][bt2][h]), gld(&g_om23p4[3][bt2][h])));
                o += m23x;
            }
            sh.fin.outs[tt][h] = o;
        }
        for (int h = tid; h < Hq; h += THREADS){
            float acc = 0.f;
            for (int d = 0; d < 32; ++d) acc += Wd[h * 32 + d] * ctx[d];
            sh.fin.wdc[h] = acc;
        }
        __syncthreads();
        int len = lens[b];
        if (tid < Tq){
            int tt = tid;
            float acc = 0.f;
            for (int d = 0; d < 32; ++d) acc += bd[d] * ctx[d];
            for (int h = 0; h < Hq; ++h) acc += sh.fin.outs[tt][h] * sh.fin.wdc[h];
            sh.fin.score[tt] = (tt < len) ? acc : -1e30f;
        }
        __syncthreads();
        if (tid == 0){
            float mx = -1e30f;
            for (int tt = 0; tt < Tq; ++tt) mx = fmaxf(mx, sh.fin.score[tt]);
            float sum = 0.f;
            for (int tt = 0; tt < Tq; ++tt){ float e = expf(sh.fin.score[tt] - mx); sh.fin.score[tt] = e; sum += e; }
            float inv = 1.f / sum;
            for (int tt = 0; tt < Tq; ++tt) sh.fin.score[tt] *= inv;
        }
        __syncthreads();
        for (int h = tid; h < Hq; h += THREADS){
            float acc = 0.f;
            for (int tt = 0; tt < Tq; ++tt) acc += sh.fin.score[tt] * sh.fin.outs[tt][h];
            sh.fin.pooled[h] = acc;
        }
        __syncthreads();
        // classifier slice: this block owns outputs [obase, obase+16); 32 h-segments, LDS reduce
        int obase = (blk & 63) * 16;
        {
            int ol = tid & 15, seg = tid >> 4;          // 32 segments of 5 h each (32*5 >= 150)
            int h0 = seg * 5, h1 = min(Hq, h0 + 5);
            float acc = 0.f;
            for (int h = h0; h < h1; ++h) acc += sh.fin.pooled[h] * Wc[h * OUTq + obase + ol];
            sh.fin.cpart[ol][seg] = acc;
        }
        __syncthreads();
        if (tid < 16){
            int o = obase + tid;
            float acc = bc[o];
            #pragma unroll
            for (int s2 = 0; s2 < 32; ++s2) acc += sh.fin.cpart[tid][s2];
            out[b * OUTq + o] = sigm(acc);
        }
    }
    publish(bar0 + 6);
}

extern "C" void kernel_launch(void* const* d_in, const int* in_sizes, int n_in,
                              void* d_out, int out_size, void* d_ws, size_t ws_size,
                              hipStream_t stream){
    const float* code_x    = (const float*)d_in[0];
    const float* divided   = (const float*)d_in[1];
    const float* neighbors = (const float*)d_in[2];
    const int*   lens      = (const int*)  d_in[3];
    const float* adj       = (const float*)d_in[4];
    const float* c_emb     = (const float*)d_in[5];
    const float* n_emb     = (const float*)d_in[6];
    const float* u_emb     = (const float*)d_in[7];
    const float* Wg        = (const float*)d_in[8];
    const float* bg        = (const float*)d_in[9];
    const float* Wi        = (const float*)d_in[10];
    const float* bi        = (const float*)d_in[11];
    const float* Wh        = (const float*)d_in[12];
    const float* bh        = (const float*)d_in[13];
    const float* Wq_       = (const float*)d_in[14];
    const float* bq_       = (const float*)d_in[15];
    const float* Wk_       = (const float*)d_in[16];
    const float* bk_       = (const float*)d_in[17];
    const float* Wv_       = (const float*)d_in[18];
    const float* bv_       = (const float*)d_in[19];
    const float* Wd_       = (const float*)d_in[20];
    const float* bd_       = (const float*)d_in[21];
    const float* ctx       = (const float*)d_in[22];
    const float* Wc_       = (const float*)d_in[23];
    const float* bc_       = (const float*)d_in[24];
    float* out = (float*)d_out;

    hipLaunchKernelGGL(k_fused, dim3(NBLK), dim3(THREADS), 0, stream,
                       code_x, divided, neighbors, lens, adj, c_emb, n_emb, u_emb,
                       Wg, bg, Wi, bi, Wh, bh, Wq_, bq_, Wk_, bk_, Wv_, bv_,
                       Wd_, bd_, ctx, Wc_, bc_, out);
}

// Round 16
// 231.759 us; speedup vs baseline: 1.2872x; 1.2872x over previous
//
#include <hip/hip_runtime.h>

#define Bq   8
#define Tq   16
#define Nq   1024
#define Cq   48
#define Gq   32
#define Hq   150
#define H3q  450
#define TAq  32
#define OUTq 1024
#define BTq  128
#define NBLK (2 * BTq)   // grid = CU count; 1 block/CU via 96KB LDS union
#define THREADS 512

#define NC_CAP 128
#define NM_CAP 64
#define NACT   (2 * NC_CAP)
#define MTILE  16
#define NMH    (NM_CAP / 2)
#define CHUNK  16        // GRU1B chain-row batch

__device__ __forceinline__ float lrelu(float x){ return x > 0.f ? x : 0.01f * x; }
__device__ __forceinline__ float sigm(float x){ return 1.f / (1.f + expf(-x)); }

// -------- cross-block data: agent-scope relaxed atomics (sc1 -> LLC); no fences anywhere ----
__device__ __align__(16) int   g_n1[BTq], g_n23[BTq], g_nchain[BTq], g_nchain2[BTq];
__device__ __align__(16) int   g_list1[BTq][NM_CAP];
__device__ __align__(16) int   g_list23[BTq][NM_CAP];   // row | (m2 ? 0x400 : 0)
__device__ __align__(16) int   g_mapc[BTq][Nq];
__device__ __align__(16) int   g_mapn[BTq][Nq];
__device__ __align__(16) int   g_chain[BTq][NM_CAP];    // (i_slot << 16) | prev_slot
__device__ __align__(16) int   g_chain2[BTq][NM_CAP];
__device__ __align__(16) int   g_cls[BTq][NM_CAP];
__device__ __align__(16) float g_co[BTq][NC_CAP][Gq];
__device__ __align__(16) float g_no[BTq][NC_CAP][Gq];
__device__ __align__(16) float g_hm23[BTq][NM_CAP][Hq];
__device__ __align__(16) float g_om23p2[2][BTq][Hq];
__device__ __align__(16) float g_hm1[BTq][NM_CAP][Hq];
__device__ __align__(16) float g_om1p2[2][BTq][Hq];
__device__ __align__(16) float g_om1c[BTq][Hq];

template<typename T>
__device__ __forceinline__ T gld(const T* p){
    return __hip_atomic_load(p, __ATOMIC_RELAXED, __HIP_MEMORY_SCOPE_AGENT);
}
template<typename T>
__device__ __forceinline__ void gst(T* p, T v){
    __hip_atomic_store(p, v, __ATOMIC_RELAXED, __HIP_MEMORY_SCOPE_AGENT);
}

// -------- per-block dataflow flags ------------------------------------------------------------
// Progress per launch: +1 CO, +2 MID, +3 GRU1; even blocks +4 after GRU1B; chain blocks
// (blk%32==0) +5 after FIN-A (deep chains); ALL blocks run FIN-B and end at +6 (replay-safe).
__device__ unsigned int g_done[NBLK][16];

__device__ __forceinline__ void publish(unsigned int val){
    asm volatile("s_waitcnt vmcnt(0)" ::: "memory");   // sc1 stores committed at L3
    __syncthreads();
    if (threadIdx.x == 0)
        __hip_atomic_store(&g_done[blockIdx.x][0], val,
                           __ATOMIC_RELAXED, __HIP_MEMORY_SCOPE_AGENT);
}

__device__ __forceinline__ void spin_ge(int b2, unsigned int tgt){
    while ((int)(__hip_atomic_load(&g_done[b2][0],
                                   __ATOMIC_RELAXED, __HIP_MEMORY_SCOPE_AGENT) - tgt) < 0)
        __builtin_amdgcn_s_sleep(4);
}

// inline gi helper: gi = bi + co @ Wi at column h
__device__ __forceinline__ void gi3(const float* co_row, const float* Wi, const float* bi, int h,
                                    float& gr, float& gz, float& gn){
    gr = bi[h]; gz = bi[Hq + h]; gn = bi[2 * Hq + h];
    #pragma unroll
    for (int g = 0; g < Gq; ++g){
        float c = co_row[g];
        const float* w = Wi + g * H3q + h;
        gr += c * w[0];
        gz += c * w[Hq];
        gn += c * w[2 * Hq];
    }
}

// -------- L3 warm-stream (inputs + weights only; scratch-warm was null in r10) ---------------
#define WARM(ptr, nfloats) { int nv_ = (nfloats) >> 2; \
    for (int i4_ = blk * THREADS + tid; i4_ < nv_; i4_ += NBLK * THREADS){ \
        float4 v_ = ((const float4*)(ptr))[i4_]; \
        wacc += v_.x + v_.y + v_.z + v_.w; } }

// -------- phase-overlaid LDS ----------------------------------------------------------------
union SharedU {
    struct {                                   // CO (~58 KB)
        unsigned char cf[Nq], nf[Nq];
        short lc[NC_CAP], ln[NC_CAP];
        short act[NACT];
        float Wg[Cq][Gq];
        float Pact[NACT][Gq];
        float A[MTILE][NACT];
    } co;
    struct {                                   // MID (~96 KB)
        unsigned char f1[Nq], f2[Nq], f3[Nq];
        short l1[NM_CAP], l23[NM_CAP];
        unsigned char wm[NMH];
        float co23[NM_CAP][Gq];
        float qr[NM_CAP][Gq];
        float q[NMH][TAq + 1];
        float k[NM_CAP][TAq + 1];
        float s[NMH][NM_CAP + 1];
        float vv[NM_CAP][Hq];
        float hm[NMH][Hq];
    } mid;
    struct {                                   // GRU1 (~68 KB)
        short map1p[Nq], map23p[Nq];
        short l1[NM_CAP];
        unsigned char cls[NM_CAP];
        int   m23l[NM_CAP];
        float co1[NMH][Gq];
        float hb[Hq];
        float ghf[H3q];
        float gi[NMH][H3q];
    } g1;
    struct {                                   // GRU1B batched (~51 KB)
        int   proc[NM_CAP];                    // packed non-deferred (i<<16|sp)
        float hb[CHUNK][Hq];
        float co[CHUNK][Gq];
        float ghf[CHUNK][H3q];
        float hm[CHUNK][Hq];
        float cmax[Hq];
    } g1b;
    struct {                                   // FIN (~16 KB)
        int   nch2[Tq];
        float co[Gq];
        float hb[Hq];
        float ghf[H3q];
        float outs[Tq][Hq];
        float wdc[Hq];
        float score[Tq];
        float pooled[Hq];
        float cpart[32][17];                   // classifier partials (32 outputs x 16 segs)
    } fin;
};

// -------- CO tile helpers: statically-indexed double-buffered adj gather ---------------------
#define CO_PREFETCH(P, kk) { int rbase_ = half + (kk) * 2 * MTILE; \
    int ntile_ = min(MTILE, (total - rbase_ + 1) / 2); int lim_ = ntile_ * total; \
    _Pragma("unroll") for (int u = 0; u < 8; ++u){ int idx_ = tid + u * THREADS; \
        if (idx_ < lim_){ int ti_ = idx_ / total, j_ = idx_ - ti_ * total; \
            P[u] = adj[(size_t)sh.co.act[rbase_ + 2 * ti_] * Nq + sh.co.act[j_]]; } } }

#define CO_STORE(P, kk) { int rbase_ = half + (kk) * 2 * MTILE; \
    int ntile_ = min(MTILE, (total - rbase_ + 1) / 2); int lim_ = ntile_ * total; \
    _Pragma("unroll") for (int u = 0; u < 8; ++u){ int idx_ = tid + u * THREADS; \
        if (idx_ < lim_){ int ti_ = idx_ / total, j_ = idx_ - ti_ * total; \
            sh.co.A[ti_][j_] = P[u]; } } }

#define CO_COMPUTE(kk) { int rbase_ = half + (kk) * 2 * MTILE; \
    int ntile_ = min(MTILE, (total - rbase_ + 1) / 2); \
    if (grp < ntile_){ int r_ = rbase_ + 2 * grp; float agg_ = 0.f; \
        _Pragma("unroll 4") for (int j_ = 0; j_ < total; ++j_) \
            agg_ += sh.co.A[grp][j_] * sh.co.Pact[j_][g]; \
        float v_ = lrelu(sh.co.Pact[r_][g] + agg_ + bgv); \
        if (r_ < nc) gst(&g_co[bt][r_][g], v_); else gst(&g_no[bt][r_ - nc][g], v_); } }

__global__ __launch_bounds__(THREADS, 1) void k_fused(
    const float* code_x, const float* divided, const float* neighbors,
    const int* lens, const float* adj, const float* c_emb, const float* n_emb,
    const float* u_emb, const float* Wg, const float* bg,
    const float* Wi, const float* bi, const float* Wh, const float* bh,
    const float* Wq_, const float* bq_, const float* Wk_, const float* bk_,
    const float* Wv_, const float* bv_, const float* Wd, const float* bd,
    const float* ctx, const float* Wc, const float* bc, float* out)
{
    __shared__ SharedU sh;
    __shared__ int s_n0, s_n1v, s_i2;
    const int tid = threadIdx.x;
    const int blk = blockIdx.x;
    const int bt   = blk >> 1;
    const int half = blk & 1;
    const int t    = bt % Tq;
    const int btp  = bt - 1;
    const unsigned int bar0 = __hip_atomic_load(&g_done[blk][0],
                                                __ATOMIC_RELAXED, __HIP_MEMORY_SCOPE_AGENT);

    // ---- L3 warm-stream (~8.3 MB) ----
    float wacc = 0.f;
    WARM(code_x,    BTq * Nq);
    WARM(neighbors, BTq * Nq);
    WARM(adj,       Nq * Nq);
    WARM(divided,   BTq * Nq * 3);
    WARM(c_emb,     Nq * Cq);
    WARM(n_emb,     Nq * Cq);
    WARM(u_emb,     Nq * Gq);
    WARM(Wi,        Gq * H3q);
    WARM(Wh,        Hq * H3q);
    WARM(Wc,        Hq * OUTq);
    WARM(Wv_,       Gq * Hq);
    WARM(Wd,        Hq * TAq);

    // ================= Phase CO =================
    {
        int wave = tid >> 6, lane = tid & 63;
        for (int n = tid; n < Nq; n += THREADS){
            sh.co.cf[n] = (code_x[bt * Nq + n]    > 0.f) ? 1 : 0;
            sh.co.nf[n] = (neighbors[bt * Nq + n] > 0.f) ? 1 : 0;
        }
        for (int i = tid; i < Cq * Gq; i += THREADS) (&sh.co.Wg[0][0])[i] = Wg[i];
        __syncthreads();
        if (wave == 0){           // compact c-active rows (ballot over LDS flags)
            int base = 0;
            for (int start = 0; start < Nq; start += 64){
                int n = start + lane;
                int pred = sh.co.cf[n];
                unsigned long long mm = __ballot(pred != 0);
                int pos = base + (int)__popcll(mm & ((1ull << lane) - 1ull));
                if (pred && pos < NC_CAP) sh.co.lc[pos] = (short)n;
                base += (int)__popcll(mm);
            }
            if (lane == 0) s_n0 = min(base, NC_CAP);
        } else if (wave == 1){    // compact nb-active rows
            int base = 0;
            for (int start = 0; start < Nq; start += 64){
                int n = start + lane;
                int pred = sh.co.nf[n];
                unsigned long long mm = __ballot(pred != 0);
                int pos = base + (int)__popcll(mm & ((1ull << lane) - 1ull));
                if (pred && pos < NC_CAP) sh.co.ln[pos] = (short)n;
                base += (int)__popcll(mm);
            }
            if (lane == 0) s_n1v = min(base, NC_CAP);
        } else {                  // clear map half (384 threads, 1024 entries)
            if (half == 0) for (int n = tid - 128; n < Nq; n += 384) gst(&g_mapc[bt][n], -1);
            else           for (int n = tid - 128; n < Nq; n += 384) gst(&g_mapn[bt][n], -1);
        }
        __syncthreads();
        int nc = s_n0, nn = s_n1v, total = nc + nn;

        for (int i = tid; i < total; i += THREADS) sh.co.act[i] = (i < nc) ? sh.co.lc[i] : sh.co.ln[i - nc];
        if (half == 0) for (int i = tid; i < nc; i += THREADS) gst(&g_mapc[bt][sh.co.lc[i]], i);
        else           for (int i = tid; i < nn; i += THREADS) gst(&g_mapn[bt][sh.co.ln[i]], i);
        __syncthreads();

        // Pact[i][g] = emb[act[i]] @ Wg
        for (int idx = tid; idx < total * Gq; idx += THREADS){
            int i = idx >> 5, g = idx & 31;
            int row = sh.co.act[i];
            const float* e = (i < nc) ? (c_emb + row * Cq) : (n_emb + row * Cq);
            float acc = 0.f;
            #pragma unroll
            for (int c = 0; c < Cq; ++c) acc += e[c] * sh.co.Wg[c][g];
            sh.co.Pact[i][g] = acc;
        }
        __syncthreads();

        // double-buffered gathered-GEMM
        int g = tid & 31, grp = tid >> 5;
        float bgv = bg[g];
        int ntiles = (total > half) ? (total - half + 2 * MTILE - 1) / (2 * MTILE) : 0;
        float pA[8], pB[8];
        if (ntiles > 0) CO_PREFETCH(pA, 0);
        for (int k = 0; k < ntiles; ){
            CO_STORE(pA, k);
            __syncthreads();
            if (k + 1 < ntiles) CO_PREFETCH(pB, k + 1);
            CO_COMPUTE(k);
            __syncthreads();
            ++k; if (k >= ntiles) break;
            CO_STORE(pB, k);
            __syncthreads();
            if (k + 1 < ntiles) CO_PREFETCH(pA, k + 1);
            CO_COMPUTE(k);
            __syncthreads();
            ++k;
        }
    }
    asm volatile("" :: "v"(wacc));   // keep warm loads live (rule #17)
    publish(bar0 + 1);
    // T14: divided prefetch flies during the spin + syncthreads below
    float dv[6];
    #pragma unroll
    for (int u = 0; u < 6; ++u) dv[u] = divided[(size_t)bt * (Nq * 3) + tid + u * THREADS];
    if (tid == 0) spin_ge(blk ^ 1, bar0 + 1);
    else if (t > 0 && tid == 1) spin_ge(2 * btp,     bar0 + 1);
    else if (t > 0 && tid == 2) spin_ge(2 * btp + 1, bar0 + 1);
    __syncthreads();

    // ================= Phase MID =================
    {
        int wave = tid >> 6, lane = tid & 63;
        #pragma unroll
        for (int u = 0; u < 6; ++u){
            int idx = tid + u * THREADS;
            int n = idx / 3, c = idx - n * 3;
            unsigned char f = (dv[u] > 0.f) ? 1 : 0;
            if (c == 0) sh.mid.f1[n] = f;
            else if (c == 1) sh.mid.f2[n] = f;
            else sh.mid.f3[n] = f;
        }
        __syncthreads();
        if (wave == 0){           // m1 list
            int base = 0;
            for (int start = 0; start < Nq; start += 64){
                int n = start + lane;
                int pred = sh.mid.f1[n];
                unsigned long long mm = __ballot(pred != 0);
                int pos = base + (int)__popcll(mm & ((1ull << lane) - 1ull));
                if (pred && pos < NM_CAP) sh.mid.l1[pos] = (short)n;
                base += (int)__popcll(mm);
            }
            if (lane == 0) s_n0 = min(base, NM_CAP);
        } else if (wave == 1){    // m23 list with m2 tag
            int base = 0;
            for (int start = 0; start < Nq; start += 64){
                int n = start + lane;
                int m2 = sh.mid.f2[n], m3 = sh.mid.f3[n];
                int pred = m2 | m3;
                unsigned long long mm = __ballot(pred != 0);
                int pos = base + (int)__popcll(mm & ((1ull << lane) - 1ull));
                if (pred && pos < NM_CAP) sh.mid.l23[pos] = (short)(n | (m2 ? 0x400 : 0));
                base += (int)__popcll(mm);
            }
            if (lane == 0) s_n1v = min(base, NM_CAP);
        }
        __syncthreads();
        int n1 = s_n0, n23 = s_n1v;
        if (half == 0){
            for (int i = tid; i < n1;  i += THREADS) gst(&g_list1[bt][i],  (int)sh.mid.l1[i]);
            for (int i = tid; i < n23; i += THREADS) gst(&g_list23[bt][i], (int)sh.mid.l23[i]);
            if (tid == 0){ gst(&g_n1[bt], n1); gst(&g_n23[bt], n23); }
        }
        if (t != 0 && n23 != 0){
            int nMy = (n23 > half) ? ((n23 - half + 1) >> 1) : 0;

            for (int il = tid; il < nMy; il += THREADS){
                int row = sh.mid.l23[2 * il + half] & 1023;
                unsigned char wmv = 0;
                if (t < Tq - 1) wmv = (divided[((size_t)(bt + 1) * Nq + row) * 3] > 0.f) ? 1 : 0;
                sh.mid.wm[il] = wmv;
            }
            for (int idx = tid; idx < n23 * Gq; idx += THREADS){
                int i = idx >> 5, g = idx & 31;
                sh.mid.co23[i][g] = gld(&g_co[bt][gld(&g_mapc[bt][sh.mid.l23[i] & 1023])][g]);
            }
            for (int idx = tid; idx < n23 * Gq; idx += THREADS){
                int i = idx >> 5, g = idx & 31;
                int e = sh.mid.l23[i], row = e & 1023;
                float qv;
                if (e & 0x400){
                    int slot = gld(&g_mapn[btp][row]);
                    qv = (slot >= 0) ? gld(&g_no[btp][slot][g]) : lrelu(bg[g]);
                } else {
                    qv = u_emb[row * Gq + g];
                }
                sh.mid.qr[i][g] = qv;
            }
            __syncthreads();
            for (int idx = tid; idx < n23 * TAq; idx += THREADS){
                int i = idx >> 5, a = idx & 31;
                float acck = bk_[a];
                #pragma unroll
                for (int g = 0; g < Gq; ++g) acck += sh.mid.co23[i][g] * Wk_[g * TAq + a];
                sh.mid.k[i][a] = acck;
            }
            for (int idx = tid; idx < nMy * TAq; idx += THREADS){
                int il = idx >> 5, a = idx & 31;
                int i = 2 * il + half;
                float accq = bq_[a];
                #pragma unroll
                for (int g = 0; g < Gq; ++g) accq += sh.mid.qr[i][g] * Wq_[g * TAq + a];
                sh.mid.q[il][a] = accq;
            }
            for (int idx = tid; idx < n23 * Hq; idx += THREADS){
                int i = idx / Hq, h = idx % Hq;
                float acc = bv_[h];
                #pragma unroll
                for (int g = 0; g < Gq; ++g) acc += sh.mid.qr[i][g] * Wv_[g * Hq + h];
                sh.mid.vv[i][h] = acc;
            }
            __syncthreads();

            const float scale = 0.17677669529663687f;   // 1/sqrt(32)
            for (int idx = tid; idx < nMy * n23; idx += THREADS){
                int il = idx / n23, j = idx % n23;
                float acc = 0.f;
                #pragma unroll
                for (int a = 0; a < TAq; ++a) acc += sh.mid.q[il][a] * sh.mid.k[j][a];
                sh.mid.s[il][j] = acc * scale;
            }
            __syncthreads();
            for (int il = tid; il < nMy; il += THREADS){
                float mx = -1e30f;
                for (int j = 0; j < n23; ++j) mx = fmaxf(mx, sh.mid.s[il][j]);
                float sum = 0.f;
                for (int j = 0; j < n23; ++j){ float e = expf(sh.mid.s[il][j] - mx); sh.mid.s[il][j] = e; sum += e; }
                float inv = 1.f / sum;
                for (int j = 0; j < n23; ++j) sh.mid.s[il][j] *= inv;
            }
            __syncthreads();
            for (int idx = tid; idx < nMy * Hq; idx += THREADS){
                int il = idx / Hq, h = idx % Hq;
                float acc = 0.f;
                for (int j = 0; j < n23; ++j) acc += sh.mid.s[il][j] * sh.mid.vv[j][h];
                sh.mid.hm[il][h] = tanhf(acc);
            }
            __syncthreads();
            for (int idx = tid; idx < nMy * Hq; idx += THREADS){
                int il = idx / Hq, h = idx % Hq;
                if (sh.mid.wm[il]) gst(&g_hm23[bt][2 * il + half][h], sh.mid.hm[il][h]);
            }
            for (int h = tid; h < Hq; h += THREADS){
                float mx = -1e30f;
                for (int il = 0; il < nMy; ++il) mx = fmaxf(mx, sh.mid.hm[il][h]);
                gst(&g_om23p2[half][bt][h], mx);
            }
        }
    }
    publish(bar0 + 2);
    if (tid == 0) spin_ge(blk ^ 1, bar0 + 2);
    else if (t > 0 && tid == 1) spin_ge(2 * btp,     bar0 + 2);
    else if (t > 0 && tid == 2) spin_ge(2 * btp + 1, bar0 + 2);
    __syncthreads();

    // ================= Phase GRU1 =================
    {
        int n1 = gld(&g_n1[bt]);
        int nMy = (n1 > half) ? ((n1 - half + 1) >> 1) : 0;
        for (int n = tid; n < Nq; n += THREADS){
            if (t >= 1) sh.g1.map1p[n] = -1;
            if (t >= 2) sh.g1.map23p[n] = -1;
        }
        for (int i = tid; i < n1; i += THREADS) sh.g1.l1[i] = (short)gld(&g_list1[bt][i]);
        __syncthreads();
        if (t >= 1){
            int n1p = gld(&g_n1[btp]);
            for (int i = tid; i < n1p; i += THREADS) sh.g1.map1p[gld(&g_list1[btp][i])] = (short)i;
            if (t >= 2){
                int n23p = gld(&g_n23[btp]);
                for (int i = tid; i < n23p; i += THREADS) sh.g1.map23p[gld(&g_list23[btp][i]) & 1023] = (short)i;
            }
        }
        __syncthreads();
        if (tid < 64){                                // classify + ballot-compact
            int i = tid;
            int cls = 0, sp = -1;
            if (i < n1 && t >= 1){
                int row = sh.g1.l1[i];
                if (sh.g1.map1p[row] >= 0){ cls = 1; sp = sh.g1.map1p[row]; }
                else if (t >= 2 && sh.g1.map23p[row] >= 0){ cls = 2; sp = sh.g1.map23p[row]; }
            }
            if (i < n1) sh.g1.cls[i] = (unsigned char)cls;
            if (half == 0 && i < n1) gst(&g_cls[bt][i], cls);
            unsigned long long mch = __ballot(cls == 1);
            unsigned long long m23 = __ballot(cls == 2 && (i & 1) == half);
            int pch = (int)__popcll(mch & ((1ull << i) - 1ull));
            int p23 = (int)__popcll(m23 & ((1ull << i) - 1ull));
            if (half == 0 && cls == 1) gst(&g_chain[bt][pch], (i << 16) | sp);
            if (cls == 2 && (i & 1) == half) sh.g1.m23l[p23] = (i << 16) | sp;
            if (i == 0){
                s_i2 = (int)__popcll(m23);
                if (half == 0) gst(&g_nchain[bt], (int)__popcll(mch));
            }
        }
        for (int idx = tid; idx < nMy * Gq; idx += THREADS){
            int il = idx >> 5, g = idx & 31;
            sh.g1.co1[il][g] = gld(&g_co[bt][gld(&g_mapc[bt][sh.g1.l1[2 * il + half]])][g]);
        }
        __syncthreads();

        // cooperative gi: thread j < 450 holds Wi column in regs
        if (tid < H3q){
            float wcol[Gq];
            #pragma unroll
            for (int g = 0; g < Gq; ++g) wcol[g] = Wi[g * H3q + tid];
            float bij = bi[tid];
            for (int il = 0; il < nMy; ++il){
                float acc = bij;
                #pragma unroll
                for (int g = 0; g < Gq; ++g) acc += sh.g1.co1[il][g] * wcol[g];
                sh.g1.gi[il][tid] = acc;
            }
        }
        __syncthreads();

        // plain rows: hp = 0, gh = bias only
        for (int idx = tid; idx < nMy * Hq; idx += THREADS){
            int il = idx / Hq, h = idx % Hq;
            int i = 2 * il + half;
            if (sh.g1.cls[i] != 0) continue;
            float gr = sh.g1.gi[il][h], gz = sh.g1.gi[il][Hq + h], gn = sh.g1.gi[il][2 * Hq + h];
            float r  = sigm(gr + bh[h]);
            float z  = sigm(gz + bh[Hq + h]);
            float ng = tanhf(gn + r * bh[2 * Hq + h]);
            sh.g1.gi[il][h] = (1.f - z) * ng;
        }
        __syncthreads();

        // m23-sourced rows (~0.5 per block)
        int nf23 = s_i2;
        for (int f = 0; f < nf23; ++f){
            int pk = sh.g1.m23l[f]; int i = pk >> 16, sp = pk & 0xffff;
            int il = i >> 1;
            for (int h = tid; h < Hq; h += THREADS) sh.g1.hb[h] = gld(&g_hm23[btp][sp][h]);
            __syncthreads();
            for (int j = tid; j < H3q; j += THREADS){
                float acc = bh[j];
                for (int k2 = 0; k2 < Hq; ++k2) acc += sh.g1.hb[k2] * Wh[k2 * H3q + j];
                sh.g1.ghf[j] = acc;
            }
            __syncthreads();
            for (int h = tid; h < Hq; h += THREADS){
                float gr = sh.g1.gi[il][h], gz = sh.g1.gi[il][Hq + h], gn = sh.g1.gi[il][2 * Hq + h];
                float r  = sigm(gr + sh.g1.ghf[h]);
                float z  = sigm(gz + sh.g1.ghf[Hq + h]);
                float ng = tanhf(gn + r * sh.g1.ghf[2 * Hq + h]);
                sh.g1.gi[il][h] = (1.f - z) * ng + z * sh.g1.hb[h];
            }
            __syncthreads();
        }

        for (int idx = tid; idx < nMy * Hq; idx += THREADS){
            int il = idx / Hq, h = idx % Hq;
            int i = 2 * il + half;
            if (sh.g1.cls[i] != 1) gst(&g_hm1[bt][i][h], sh.g1.gi[il][h]);
        }
        for (int h = tid; h < Hq; h += THREADS){
            float mx = -1e30f;
            for (int il = 0; il < nMy; ++il)
                if (sh.g1.cls[2 * il + half] != 1) mx = fmaxf(mx, sh.g1.gi[il][h]);
            gst(&g_om1p2[half][bt][h], mx);
        }
    }
    publish(bar0 + 3);

    // ================= Phase GRU1B (even blocks) + FIN-A (chain blocks) ========================
    if (half == 0){
        if (t > 0){
            if (tid == 0) spin_ge(2 * btp,     bar0 + 3);
            else if (tid == 1) spin_ge(2 * btp + 1, bar0 + 3);
        }
        __syncthreads();
        {   // BATCHED chain rows (mutually independent; CHUNK at a time)
            int nch = (t > 0) ? gld(&g_nchain[bt]) : 0;
            for (int h = tid; h < Hq; h += THREADS) sh.g1b.cmax[h] = -1e30f;
            if (tid < 64){
                int c = tid;
                int pk = 0, defer = 0;
                if (c < nch){
                    pk = gld(&g_chain[bt][c]);
                    int sp = pk & 0xffff;
                    defer = (gld(&g_cls[btp][sp]) == 1) ? 1 : 0;
                }
                unsigned long long md = __ballot((c < nch) && defer);
                unsigned long long mp = __ballot((c < nch) && !defer);
                int pos  = (int)__popcll(md & ((1ull << c) - 1ull));
                int ppos = (int)__popcll(mp & ((1ull << c) - 1ull));
                if ((c < nch) && defer)  gst(&g_chain2[bt][pos], pk);
                if ((c < nch) && !defer) sh.g1b.proc[ppos] = pk;
                if (c == 0){
                    gst(&g_nchain2[bt], (int)__popcll(md));
                    s_i2 = (int)__popcll(mp);
                }
            }
            __syncthreads();
            int nproc = s_i2;
            for (int cb = 0; cb < nproc; cb += CHUNK){
                int nc2 = min(CHUNK, nproc - cb);
                for (int idx = tid; idx < nc2 * Hq; idx += THREADS){
                    int c = idx / Hq, h = idx % Hq;
                    int sp = sh.g1b.proc[cb + c] & 0xffff;
                    sh.g1b.hb[c][h] = gld(&g_hm1[btp][sp][h]);
                }
                for (int idx = tid; idx < nc2 * Gq; idx += THREADS){
                    int c = idx >> 5, g = idx & 31;
                    int i = sh.g1b.proc[cb + c] >> 16;
                    sh.g1b.co[c][g] = gld(&g_co[bt][gld(&g_mapc[bt][gld(&g_list1[bt][i])])][g]);
                }
                __syncthreads();
                for (int idx = tid; idx < nc2 * H3q; idx += THREADS){
                    int c = idx / H3q, j = idx - c * H3q;
                    float acc = bh[j];
                    for (int k2 = 0; k2 < Hq; ++k2) acc += sh.g1b.hb[c][k2] * Wh[k2 * H3q + j];
                    sh.g1b.ghf[c][j] = acc;
                }
                __syncthreads();
                for (int idx = tid; idx < nc2 * Hq; idx += THREADS){
                    int c = idx / Hq, h = idx % Hq;
                    int i = sh.g1b.proc[cb + c] >> 16;
                    float gr, gz, gn;
                    gi3(sh.g1b.co[c], Wi, bi, h, gr, gz, gn);
                    float r  = sigm(gr + sh.g1b.ghf[c][h]);
                    float z  = sigm(gz + sh.g1b.ghf[c][Hq + h]);
                    float ng = tanhf(gn + r * sh.g1b.ghf[c][2 * Hq + h]);
                    float v  = (1.f - z) * ng + z * sh.g1b.hb[c][h];
                    gst(&g_hm1[bt][i][h], v);
                    sh.g1b.hm[c][h] = v;
                }
                __syncthreads();
                for (int h = tid; h < Hq; h += THREADS){
                    float mx = sh.g1b.cmax[h];
                    for (int c = 0; c < nc2; ++c) mx = fmaxf(mx, sh.g1b.hm[c][h]);
                    sh.g1b.cmax[h] = mx;
                }
                __syncthreads();
            }
            for (int h = tid; h < Hq; h += THREADS) gst(&g_om1c[bt][h], sh.g1b.cmax[h]);
        }
        publish(bar0 + 4);

        if ((blk & 31) == 0){
            // ---- FIN-A (chain blocks): deep chains, serial over t ----
            int b = blk >> 5;
            if (tid < 16) spin_ge(32 * b + 2 * tid, bar0 + 4);   // all even blocks of b
            __syncthreads();
            if (tid < Tq) sh.fin.nch2[tid] = (tid > 0) ? gld(&g_nchain2[b * Tq + tid]) : 0;
            __syncthreads();
            for (int tt = 1; tt < Tq; ++tt){
                int bt2 = b * Tq + tt, btp2 = bt2 - 1;
                int nch2 = sh.fin.nch2[tt];
                for (int c = 0; c < nch2; ++c){
                    int pk = gld(&g_chain2[bt2][c]); int i = pk >> 16, sp = pk & 0xffff;
                    if (tid < Gq) sh.fin.co[tid] = gld(&g_co[bt2][gld(&g_mapc[bt2][gld(&g_list1[bt2][i])])][tid]);
                    for (int h = tid; h < Hq; h += THREADS) sh.fin.hb[h] = gld(&g_hm1[btp2][sp][h]);
                    __syncthreads();
                    for (int j = tid; j < H3q; j += THREADS){
                        float acc = bh[j];
                        for (int k2 = 0; k2 < Hq; ++k2) acc += sh.fin.hb[k2] * Wh[k2 * H3q + j];
                        sh.fin.ghf[j] = acc;
                    }
                    __syncthreads();
                    for (int h = tid; h < Hq; h += THREADS){
                        float gr, gz, gn;
                        gi3(sh.fin.co, Wi, bi, h, gr, gz, gn);
                        float r  = sigm(gr + sh.fin.ghf[h]);
                        float z  = sigm(gz + sh.fin.ghf[Hq + h]);
                        float ng = tanhf(gn + r * sh.fin.ghf[2 * Hq + h]);
                        gst(&g_hm1[bt2][i][h], (1.f - z) * ng + z * sh.fin.hb[h]);
                    }
                    __syncthreads();
                }
            }
            publish(bar0 + 5);
        }
    }

    // ================= Phase FIN-B (ALL 256 blocks; 32 per b, disjoint 32-output slices) =======
    {
        int b = blk >> 5;
        // wait: chain block of b >= +5 (implies all evens of b >= +4); odd blocks of b >= +3
        if (tid == 0) spin_ge(32 * b, bar0 + 5);
        else if (tid >= 1 && tid < 17) spin_ge(32 * b + 2 * (tid - 1) + 1, bar0 + 3);
        __syncthreads();

        if (tid < Tq) sh.fin.nch2[tid] = (tid > 0) ? gld(&g_nchain2[b * Tq + tid]) : 0;
        __syncthreads();
        // redundant (per-block) outs finalize + temporal attention; LDS-only
        for (int idx = tid; idx < Tq * Hq; idx += THREADS){
            int tt = idx / Hq, h = idx % Hq;
            int bt2 = b * Tq + tt;
            int n1 = gld(&g_n1[bt2]), n23 = (tt > 0) ? gld(&g_n23[bt2]) : 0;
            float o = 0.f;
            if (n1 > 0){
                float mx = fmaxf(fmaxf(gld(&g_om1p2[0][bt2][h]), gld(&g_om1p2[1][bt2][h])),
                                 gld(&g_om1c[bt2][h]));
                int nd = sh.fin.nch2[tt];
                for (int c = 0; c < nd; ++c){
                    int i = gld(&g_chain2[bt2][c]) >> 16;
                    mx = fmaxf(mx, gld(&g_hm1[bt2][i][h]));
                }
                o = mx;
            }
            if (n23 > 0) o += fmaxf(gld(&g_om23p2[0][bt2][h]), gld(&g_om23p2[1][bt2][h]));
            sh.fin.outs[tt][h] = o;
        }
        for (int h = tid; h < Hq; h += THREADS){
            float acc = 0.f;
            for (int d = 0; d < 32; ++d) acc += Wd[h * 32 + d] * ctx[d];
            sh.fin.wdc[h] = acc;
        }
        __syncthreads();
        int len = lens[b];
        if (tid < Tq){
            int tt = tid;
            float acc = 0.f;
            for (int d = 0; d < 32; ++d) acc += bd[d] * ctx[d];
            for (int h = 0; h < Hq; ++h) acc += sh.fin.outs[tt][h] * sh.fin.wdc[h];
            sh.fin.score[tt] = (tt < len) ? acc : -1e30f;
        }
        __syncthreads();
        if (tid == 0){
            float mx = -1e30f;
            for (int tt = 0; tt < Tq; ++tt) mx = fmaxf(mx, sh.fin.score[tt]);
            float sum = 0.f;
            for (int tt = 0; tt < Tq; ++tt){ float e = expf(sh.fin.score[tt] - mx); sh.fin.score[tt] = e; sum += e; }
            float inv = 1.f / sum;
            for (int tt = 0; tt < Tq; ++tt) sh.fin.score[tt] *= inv;
        }
        __syncthreads();
        for (int h = tid; h < Hq; h += THREADS){
            float acc = 0.f;
            for (int tt = 0; tt < Tq; ++tt) acc += sh.fin.score[tt] * sh.fin.outs[tt][h];
            sh.fin.pooled[h] = acc;
        }
        __syncthreads();
        // classifier slice: this block owns outputs [obase, obase+32); 16 h-segments, LDS reduce
        int obase = (blk & 31) * 32;
        {
            int ol = tid & 31, seg = tid >> 5;          // 16 segments of 10 h each
            int h0 = seg * 10, h1 = min(Hq, h0 + 10);
            float acc = 0.f;
            for (int h = h0; h < h1; ++h) acc += sh.fin.pooled[h] * Wc[h * OUTq + obase + ol];
            sh.fin.cpart[ol][seg] = acc;
        }
        __syncthreads();
        if (tid < 32){
            int o = obase + tid;
            float acc = bc[o];
            #pragma unroll
            for (int s2 = 0; s2 < 16; ++s2) acc += sh.fin.cpart[tid][s2];
            out[b * OUTq + o] = sigm(acc);
        }
    }
    publish(bar0 + 6);
}

extern "C" void kernel_launch(void* const* d_in, const int* in_sizes, int n_in,
                              void* d_out, int out_size, void* d_ws, size_t ws_size,
                              hipStream_t stream){
    const float* code_x    = (const float*)d_in[0];
    const float* divided   = (const float*)d_in[1];
    const float* neighbors = (const float*)d_in[2];
    const int*   lens      = (const int*)  d_in[3];
    const float* adj       = (const float*)d_in[4];
    const float* c_emb     = (const float*)d_in[5];
    const float* n_emb     = (const float*)d_in[6];
    const float* u_emb     = (const float*)d_in[7];
    const float* Wg        = (const float*)d_in[8];
    const float* bg        = (const float*)d_in[9];
    const float* Wi        = (const float*)d_in[10];
    const float* bi        = (const float*)d_in[11];
    const float* Wh        = (const float*)d_in[12];
    const float* bh        = (const float*)d_in[13];
    const float* Wq_       = (const float*)d_in[14];
    const float* bq_       = (const float*)d_in[15];
    const float* Wk_       = (const float*)d_in[16];
    const float* bk_       = (const float*)d_in[17];
    const float* Wv_       = (const float*)d_in[18];
    const float* bv_       = (const float*)d_in[19];
    const float* Wd_       = (const float*)d_in[20];
    const float* bd_       = (const float*)d_in[21];
    const float* ctx       = (const float*)d_in[22];
    const float* Wc_       = (const float*)d_in[23];
    const float* bc_       = (const float*)d_in[24];
    float* out = (float*)d_out;

    hipLaunchKernelGGL(k_fused, dim3(NBLK), dim3(THREADS), 0, stream,
                       code_x, divided, neighbors, lens, adj, c_emb, n_emb, u_emb,
                       Wg, bg, Wi, bi, Wh, bh, Wq_, bq_, Wk_, bk_, Wv_, bv_,
                       Wd_, bd_, ctx, Wc_, bc_, out);
}